// Round 14
// baseline (285.889 us; speedup 1.0000x reference)
//
#include <hip/hip_runtime.h>

#define NCACHE 384

__device__ __forceinline__ unsigned int sortable_bits(float f) {
    unsigned int u = __float_as_uint(f);
    return (u & 0x80000000u) ? ~u : (u | 0x80000000u);
}

// All score words sv lie in (0x3FFFFFFF, 0xC0000000): |score| < 2.0 by
// construction (dot products of unit vectors; exact 0 -> 0x80000000).
// Hence a-k is in (-2^31, 2^31) for any two words and the SIGN BIT of
// (a-k) mod 2^32 equals (a<k) unsigned. Pure-VGPR compare counting:
// NO v_cmp / v_addc / VCC / SGPR traffic in the hot loop (testing the
// "mask-port ops cost ~2x" theory behind the R4-R13 ~230us wall).

#define P_LT(J, K, D) "v_sub_u32 " D ", " J ", " K "\n\t"   /* sign: v<k  */
#define P_LE(J, K, D) "v_sub_u32 " D ", " K ", " J "\n\t"   /* sign: k<v  */
#define SH(D)         "v_ashrrev_i32 " D ", 31, " D "\n\t"  /* 0 or -1    */
#define A_LT(R, D)    "v_sub_u32 " R ", " R ", " D "\n\t"   /* r += (v<k) */
#define A_LE(R, D)    "v_add_u32 " R ", " R ", " D "\n\t"   /* r -= (k<v); +32/chunk bias later */

// two j-values vs all 4 keys; producer->consumer distance 8 instrs.
#define J2(Ja, Jb, P0, A0, P1, A1, P2, A2, P3, A3)              \
    P0(Ja, "%[k0]", "%[d0]") P1(Ja, "%[k1]", "%[d1]")           \
    P2(Ja, "%[k2]", "%[d2]") P3(Ja, "%[k3]", "%[d3]")           \
    P0(Jb, "%[k0]", "%[d4]") P1(Jb, "%[k1]", "%[d5]")           \
    P2(Jb, "%[k2]", "%[d6]") P3(Jb, "%[k3]", "%[d7]")           \
    SH("%[d0]") SH("%[d1]") SH("%[d2]") SH("%[d3]")             \
    SH("%[d4]") SH("%[d5]") SH("%[d6]") SH("%[d7]")             \
    A0("%[r0]", "%[d0]") A1("%[r1]", "%[d1]")                   \
    A2("%[r2]", "%[d2]") A3("%[r3]", "%[d3]")                   \
    A0("%[r0]", "%[d4]") A1("%[r1]", "%[d5]")                   \
    A2("%[r2]", "%[d6]") A3("%[r3]", "%[d7]")

// stable-tie for two own-chunk j's: r += (v==k) & (jo<l5), bit jo of M=(1<<l5)-1.
#define TIE2(Ja, JOa, Jb, JOb, K, R)                            \
    "v_xor_b32 %[x0], " Ja ", " K "\n\t"                        \
    "v_xor_b32 %[x1], " Jb ", " K "\n\t"                        \
    "v_min_u32 %[x0], 1, %[x0]\n\t"                             \
    "v_min_u32 %[x1], 1, %[x1]\n\t"                             \
    "v_bfe_u32 %[x2], %[M], " JOa ", 1\n\t"                     \
    "v_bfe_u32 %[x3], %[M], " JOb ", 1\n\t"                     \
    "v_bfi_b32 %[x0], %[x0], 0, %[x2]\n\t"                      \
    "v_bfi_b32 %[x1], %[x1], 0, %[x3]\n\t"                      \
    "v_add_u32 " R ", " R ", %[x0]\n\t"                         \
    "v_add_u32 " R ", " R ", %[x1]\n\t"

#define ASM_IO                                                          \
    : [r0]"+v"(r0), [r1]"+v"(r1), [r2]"+v"(r2), [r3]"+v"(r3),           \
      [d0]"=&v"(d0), [d1]"=&v"(d1), [d2]"=&v"(d2), [d3]"=&v"(d3),       \
      [d4]"=&v"(d4), [d5]"=&v"(d5), [d6]"=&v"(d6), [d7]"=&v"(d7),       \
      [x0]"=&v"(x0), [x1]"=&v"(x1), [x2]"=&v"(x2), [x3]"=&v"(x3)        \
    : [a]"v"(q.x), [b]"v"(q.y), [c]"v"(q.z), [d]"v"(q.w),               \
      [k0]"v"(vk0), [k1]"v"(vk1), [k2]"v"(vk2), [k3]"v"(vk3), [M]"v"(Mmask)

#define OWN_U4(Q, JO0, JO1, JO2, JO3, P0,A0,P1,A1,P2,A2,P3,A3, KO, RO)  \
    do { const uint4 q = (Q);                                           \
        asm(J2("%[a]", "%[b]", P0,A0,P1,A1,P2,A2,P3,A3)                 \
            J2("%[c]", "%[d]", P0,A0,P1,A1,P2,A2,P3,A3)                 \
            TIE2("%[a]", JO0, "%[b]", JO1, KO, RO)                      \
            TIE2("%[c]", JO2, "%[d]", JO3, KO, RO)                      \
            ASM_IO);                                                    \
    } while (0)

#define OWN_BLOCK(C, P0,A0,P1,A1,P2,A2,P3,A3, KO, RO)                               \
    OWN_U4(vq[(C)*8+0], "0","1","2","3",     P0,A0,P1,A1,P2,A2,P3,A3, KO, RO);      \
    OWN_U4(vq[(C)*8+1], "4","5","6","7",     P0,A0,P1,A1,P2,A2,P3,A3, KO, RO);      \
    OWN_U4(vq[(C)*8+2], "8","9","10","11",   P0,A0,P1,A1,P2,A2,P3,A3, KO, RO);      \
    OWN_U4(vq[(C)*8+3], "12","13","14","15", P0,A0,P1,A1,P2,A2,P3,A3, KO, RO);      \
    OWN_U4(vq[(C)*8+4], "16","17","18","19", P0,A0,P1,A1,P2,A2,P3,A3, KO, RO);      \
    OWN_U4(vq[(C)*8+5], "20","21","22","23", P0,A0,P1,A1,P2,A2,P3,A3, KO, RO);      \
    OWN_U4(vq[(C)*8+6], "24","25","26","27", P0,A0,P1,A1,P2,A2,P3,A3, KO, RO);      \
    OWN_U4(vq[(C)*8+7], "28","29","30","31", P0,A0,P1,A1,P2,A2,P3,A3, KO, RO);

// 256 threads = 4 waves; each HALF-WAVE handles one b (8 b per block).
// Lane (wave w, half h, l5) owns m-keys m = c*32+l5, c=0..3.
// rank(m_c) = lt(own chunk) + tie(own, jo<l5) + lt(chunks>c) + le(chunks<c)
//             with le accumulated as -(k<v) and +32*c bias at the end.
__global__ __launch_bounds__(256, 4) void fused_kernel(
    const float*  __restrict__ cache,        // (384,5)
    const float*  __restrict__ refdirs,      // (B,3)
    const float*  __restrict__ normal,       // (B,3)
    const float4* __restrict__ samp_rays4,   // B*96 float4
    const float4* __restrict__ samp_mip4,    // B*32 float4
    float* __restrict__ out, int B)
{
#pragma clang fp contract(off)
    __shared__ __align__(16) float4 scache[NCACHE];          // dir.xyz, mip
    __shared__ __align__(16) unsigned int vals[8][NCACHE];   // per-b sortable words
    __shared__ unsigned int bitmap[8][12];

    const int tid  = threadIdx.x;
    const int wave = tid >> 6;
    const int lane = tid & 63;
    const int h    = lane >> 5;
    const int l5   = lane & 31;
    const int vidx = wave * 2 + h;
    const int myb  = blockIdx.x * 8 + vidx;

    // Pass-through copies done up-front (load -> store), freeing the VGPRs
    // before the rank loop instead of holding 16 f4 registers across it.
    {
        float4* out4     = (float4*)out;
        float4* out_mip4 = (float4*)(out + (size_t)B * 768);
        const int bbase = blockIdx.x * 8;
#pragma unroll
        for (int s = 0; s < 4; ++s) {
            const int i  = tid + s * 256;
            const int bb = bbase + (i >> 7), off = i & 127;
            if (off < 96) {
                out4[(size_t)bb * 192 + off] = samp_rays4[(size_t)bb * 96 + off];
            } else {
                out_mip4[(size_t)bb * 64 + (off - 96)] = samp_mip4[(size_t)bb * 32 + (off - 96)];
            }
        }
    }

    // Stage cache into LDS as float4 (cooperative, once per block)
    for (int m = tid; m < NCACHE; m += 256) {
        scache[m] = make_float4(cache[m * 5 + 0], cache[m * 5 + 1],
                                cache[m * 5 + 2], cache[m * 5 + 3]);
    }
    if (tid < 96) (&bitmap[0][0])[tid] = 0u;

    const float nx = normal[myb * 3 + 0], ny = normal[myb * 3 + 1], nz = normal[myb * 3 + 2];
    const float rx = refdirs[myb * 3 + 0], ry = refdirs[myb * 3 + 1], rz = refdirs[myb * 3 + 2];

    __syncthreads();

    // Scores: m = c*32 + l5, c = 0..11. FMA left-chains (bit-exact vs
    // reference); -0.0 canonicalized to +0.0.
    unsigned int vk0 = 0, vk1 = 0, vk2 = 0, vk3 = 0;
#pragma unroll
    for (int c = 0; c < 12; ++c) {
        const int m = c * 32 + l5;
        const float4 d = scache[m];
        float hemi = __builtin_fmaf(nz, d.z, __builtin_fmaf(ny, d.y, nx * d.x));
        float sim  = __builtin_fmaf(rz, d.z, __builtin_fmaf(ry, d.y, rx * d.x));
        float val  = (hemi > 0.0f) ? -sim : 0.0f;
        val = val + 0.0f;
        const unsigned int sv = sortable_bits(val);
        vals[vidx][m] = sv;
        if (c == 0) vk0 = sv;
        if (c == 1) vk1 = sv;
        if (c == 2) vk2 = sv;
        if (c == 3) vk3 = sv;
    }
    // vals[vidx] written and read by the SAME half-wave; DS ops of one wave
    // complete in order -> no barrier (proven R8-R13).

    const uint4* vq = (const uint4*)&vals[vidx][0];
    const unsigned int Mmask = (1u << l5) - 1u;
    unsigned int r0 = 0, r1 = 0, r2 = 0, r3 = 0;
    unsigned int d0, d1, d2, d3, d4, d5, d6, d7, x0, x1, x2, x3;

    // j-blocks 0..3 (the m-chunks): key<C -> lt, key>C -> le, key==C -> lt+tie.
    OWN_BLOCK(0, P_LT,A_LT, P_LE,A_LE, P_LE,A_LE, P_LE,A_LE, "%[k0]", "%[r0]");
    OWN_BLOCK(1, P_LT,A_LT, P_LT,A_LT, P_LE,A_LE, P_LE,A_LE, "%[k1]", "%[r1]");
    OWN_BLOCK(2, P_LT,A_LT, P_LT,A_LT, P_LT,A_LT, P_LE,A_LE, "%[k2]", "%[r2]");
    OWN_BLOCK(3, P_LT,A_LT, P_LT,A_LT, P_LT,A_LT, P_LT,A_LT, "%[k3]", "%[r3]");

    // j-blocks 4..11 (j >= 128): strictly above all m-keys -> lt only.
#pragma unroll 4
    for (int i = 32; i < 96; ++i) {
        const uint4 q = vq[i];
        asm(J2("%[a]", "%[b]", P_LT,A_LT, P_LT,A_LT, P_LT,A_LT, P_LT,A_LT)
            J2("%[c]", "%[d]", P_LT,A_LT, P_LT,A_LT, P_LT,A_LT, P_LT,A_LT)
            ASM_IO);
    }

    // le bias: key c saw 32*c le-pairs accumulated as -(k<v).
    r1 += 32u; r2 += 64u; r3 += 96u;

    // Ranks are distinct in [0,384). Output slot = #{selected ranks < r}.
    atomicOr(&bitmap[vidx][r0 >> 5], 1u << (r0 & 31));
    atomicOr(&bitmap[vidx][r1 >> 5], 1u << (r1 & 31));
    atomicOr(&bitmap[vidx][r2 >> 5], 1u << (r2 & 31));
    atomicOr(&bitmap[vidx][r3 >> 5], 1u << (r3 & 31));

    float* out_rays = out;
    float* out_mip  = out + (size_t)B * 768;

#pragma unroll
    for (int c = 0; c < 4; ++c) {
        const unsigned int r = (c == 0) ? r0 : (c == 1) ? r1 : (c == 2) ? r2 : r3;
        const int wi = (int)(r >> 5);
        int s = __popc(bitmap[vidx][wi] & ((1u << (r & 31)) - 1u));
        for (int w = 0; w < wi; ++w) s += __popc(bitmap[vidx][w]);
        const float4 g = scache[r];
        const size_t rb = (size_t)myb * 768 + 384 + (size_t)s * 3;
        out_rays[rb + 0] = g.x;
        out_rays[rb + 1] = g.y;
        out_rays[rb + 2] = g.z;
        out_mip[(size_t)myb * 256 + 128 + s] = g.w;
    }
}

extern "C" void kernel_launch(void* const* d_in, const int* in_sizes, int n_in,
                              void* d_out, int out_size, void* d_ws, size_t ws_size,
                              hipStream_t stream) {
    const float* cache       = (const float*)d_in[0];
    const float* refdirs     = (const float*)d_in[1];
    const float* normal      = (const float*)d_in[2];
    const float* samp_rays   = (const float*)d_in[3];
    const float* samp_mipval = (const float*)d_in[4];
    float* out = (float*)d_out;

    const int B = in_sizes[1] / 3;  // 65536

    fused_kernel<<<B / 8, 256, 0, stream>>>(cache, refdirs, normal,
                                            (const float4*)samp_rays,
                                            (const float4*)samp_mipval,
                                            out, B);
}

// Round 15
// 203.080 us; speedup vs baseline: 1.4078x; 1.4078x over previous
//
#include <hip/hip_runtime.h>

#define NCACHE 384

__device__ __forceinline__ unsigned int sortable_bits(float f) {
    unsigned int u = __float_as_uint(f);
    return (u & 0x80000000u) ? ~u : (u | 0x80000000u);
}

struct __align__(16) u64x2 { unsigned long long x, y; };

// Champion structure (R9 submission, 204.9us) with ONE change: phases A/B/C
// compare the canonicalized score FLOATS (v_cmp_lt_f32 / v_cmp_le_f32 on raw
// bits) instead of unsigned compares on sortable bits. Order is identical
// (no NaN, no -0.0 stored), so results are bit-exact. Tests whether int VALU
// is half-rate vs float on CDNA4 (the last theory standing for the ~4.3
// cyc/instr observed across R9-R14 at VALUBusy ~90-100%).
__global__ __launch_bounds__(256) void fused_kernel(
    const float*  __restrict__ cache,        // (384,5)
    const float*  __restrict__ refdirs,      // (B,3)
    const float*  __restrict__ normal,       // (B,3)
    const float4* __restrict__ samp_rays4,   // B*96 float4
    const float4* __restrict__ samp_mip4,    // B*32 float4
    float* __restrict__ out, int B)
{
#pragma clang fp contract(off)
    __shared__ float sdx[NCACHE], sdy[NCACHE], sdz[NCACHE], smip[NCACHE];
    __shared__ __align__(16) unsigned int vals[4][NCACHE];      // raw float bits
    __shared__ __align__(16) unsigned long long keys64[4][128]; // (sortable<<32)|idx
    __shared__ unsigned int bitmap[4][12];

    const int tid  = threadIdx.x;
    const int wave = tid >> 6;
    const int lane = tid & 63;
    const int b    = blockIdx.x * 4 + wave;

    // Early-issue pass-through copy loads (hide HBM under the rank loop).
    const int b0 = blockIdx.x * 4;
    const int i0 = tid, i1 = tid + 256;
    const int bb0 = b0 + (i0 >> 7), off0 = i0 & 127;
    const int bb1 = b0 + (i1 >> 7), off1 = i1 & 127;
    const float4 c0 = (off0 < 96) ? samp_rays4[(size_t)bb0 * 96 + off0]
                                  : samp_mip4[(size_t)bb0 * 32 + (off0 - 96)];
    const float4 c1 = (off1 < 96) ? samp_rays4[(size_t)bb1 * 96 + off1]
                                  : samp_mip4[(size_t)bb1 * 32 + (off1 - 96)];

    // Stage cache into LDS (cooperative, once per block)
    for (int m = tid; m < NCACHE; m += 256) {
        sdx[m]  = cache[m * 5 + 0];
        sdy[m]  = cache[m * 5 + 1];
        sdz[m]  = cache[m * 5 + 2];
        smip[m] = cache[m * 5 + 3];
    }
    if (tid < 48) (&bitmap[0][0])[tid] = 0u;

    const float nx = normal[b * 3 + 0], ny = normal[b * 3 + 1], nz = normal[b * 3 + 2];
    const float rx = refdirs[b * 3 + 0], ry = refdirs[b * 3 + 1], rz = refdirs[b * 3 + 2];

    __syncthreads();

    // Scores (FMA left-chains, bit-exact vs reference; -0.0 -> +0.0).
    // vals: raw float bits (for f32 compares). keys64: sortable<<32|idx for
    // the exact stable own-chunk compare.
    unsigned int vk0 = 0, vk1 = 0, sk0 = 0, sk1 = 0;
#pragma unroll
    for (int c = 0; c < 6; ++c) {
        const int m = c * 64 + lane;
        float dx = sdx[m], dy = sdy[m], dz = sdz[m];
        float hemi = __builtin_fmaf(nz, dz, __builtin_fmaf(ny, dy, nx * dx));
        float sim  = __builtin_fmaf(rz, dz, __builtin_fmaf(ry, dy, rx * dx));
        float val  = (hemi > 0.0f) ? -sim : 0.0f;
        val = val + 0.0f;
        const unsigned int fv = __float_as_uint(val);
        vals[wave][m] = fv;
        if (c < 2) {
            const unsigned int sv = sortable_bits(val);
            keys64[wave][m] = ((unsigned long long)sv << 32) | (unsigned int)m;
            if (c == 0) { vk0 = fv; sk0 = sv; }
            else        { vk1 = fv; sk1 = sv; }
        }
    }
    // Same-wave LDS write->read: DS pipe in-order per wave (proven R8-R14).

    const unsigned long long K0 = ((unsigned long long)sk0 << 32) | (unsigned int)lane;
    const unsigned long long K1 = ((unsigned long long)sk1 << 32) | (unsigned int)(lane + 64);

    const uint4*  v4 = (const uint4*)&vals[wave][0];
    const u64x2*  k2 = (const u64x2*)&keys64[wave][0];
    unsigned int r0 = 0, r1 = 0;
    unsigned long long sc;

    // Phase A: chunks 2..5 (above both keys): float-lt for r0 and r1.
#pragma unroll 8
    for (int i = 32; i < 96; ++i) {
        const uint4 q = v4[i];
        asm("v_cmp_lt_f32 vcc, %[a], %[k0]\n\t"
            "v_cmp_lt_f32 %[sc], %[a], %[k1]\n\t"
            "v_addc_co_u32 %[r0], vcc, 0, %[r0], vcc\n\t"
            "v_addc_co_u32 %[r1], %[sc], 0, %[r1], %[sc]\n\t"
            "v_cmp_lt_f32 vcc, %[b], %[k0]\n\t"
            "v_cmp_lt_f32 %[sc], %[b], %[k1]\n\t"
            "v_addc_co_u32 %[r0], vcc, 0, %[r0], vcc\n\t"
            "v_addc_co_u32 %[r1], %[sc], 0, %[r1], %[sc]\n\t"
            "v_cmp_lt_f32 vcc, %[c], %[k0]\n\t"
            "v_cmp_lt_f32 %[sc], %[c], %[k1]\n\t"
            "v_addc_co_u32 %[r0], vcc, 0, %[r0], vcc\n\t"
            "v_addc_co_u32 %[r1], %[sc], 0, %[r1], %[sc]\n\t"
            "v_cmp_lt_f32 vcc, %[d], %[k0]\n\t"
            "v_cmp_lt_f32 %[sc], %[d], %[k1]\n\t"
            "v_addc_co_u32 %[r0], vcc, 0, %[r0], vcc\n\t"
            "v_addc_co_u32 %[r1], %[sc], 0, %[r1], %[sc]"
            : [r0]"+v"(r0), [r1]"+v"(r1), [sc]"=&s"(sc)
            : [a]"v"(q.x), [b]"v"(q.y), [c]"v"(q.z), [d]"v"(q.w),
              [k0]"v"(vk0), [k1]"v"(vk1)
            : "vcc");
    }

    // Phase B: chunk 0 (below key1): float-le for r1.
#pragma unroll 8
    for (int i = 0; i < 16; ++i) {
        const uint4 q = v4[i];
        asm("v_cmp_le_f32 vcc, %[a], %[k1]\n\t"
            "v_cmp_le_f32 %[sc], %[b], %[k1]\n\t"
            "v_addc_co_u32 %[r1], vcc, 0, %[r1], vcc\n\t"
            "v_addc_co_u32 %[r1], %[sc], 0, %[r1], %[sc]\n\t"
            "v_cmp_le_f32 vcc, %[c], %[k1]\n\t"
            "v_cmp_le_f32 %[sc], %[d], %[k1]\n\t"
            "v_addc_co_u32 %[r1], vcc, 0, %[r1], vcc\n\t"
            "v_addc_co_u32 %[r1], %[sc], 0, %[r1], %[sc]"
            : [r1]"+v"(r1), [sc]"=&s"(sc)
            : [a]"v"(q.x), [b]"v"(q.y), [c]"v"(q.z), [d]"v"(q.w), [k1]"v"(vk1)
            : "vcc");
    }

    // Phase C: chunk 1 (above key0): float-lt for r0.
#pragma unroll 8
    for (int i = 16; i < 32; ++i) {
        const uint4 q = v4[i];
        asm("v_cmp_lt_f32 vcc, %[a], %[k0]\n\t"
            "v_cmp_lt_f32 %[sc], %[b], %[k0]\n\t"
            "v_addc_co_u32 %[r0], vcc, 0, %[r0], vcc\n\t"
            "v_addc_co_u32 %[r0], %[sc], 0, %[r0], %[sc]\n\t"
            "v_cmp_lt_f32 vcc, %[c], %[k0]\n\t"
            "v_cmp_lt_f32 %[sc], %[d], %[k0]\n\t"
            "v_addc_co_u32 %[r0], vcc, 0, %[r0], vcc\n\t"
            "v_addc_co_u32 %[r0], %[sc], 0, %[r0], %[sc]"
            : [r0]"+v"(r0), [sc]"=&s"(sc)
            : [a]"v"(q.x), [b]"v"(q.y), [c]"v"(q.z), [d]"v"(q.w), [k0]"v"(vk0)
            : "vcc");
    }

    // Phase D: own chunk of key0 (j in [0,64)): exact u64 stable compare.
#pragma unroll 8
    for (int i = 0; i < 32; ++i) {
        const u64x2 kk = k2[i];
        asm("v_cmp_lt_u64 vcc, %[x], %[K]\n\t"
            "v_cmp_lt_u64 %[sc], %[y], %[K]\n\t"
            "v_addc_co_u32 %[r0], vcc, 0, %[r0], vcc\n\t"
            "v_addc_co_u32 %[r0], %[sc], 0, %[r0], %[sc]"
            : [r0]"+v"(r0), [sc]"=&s"(sc)
            : [x]"v"(kk.x), [y]"v"(kk.y), [K]"v"(K0)
            : "vcc");
    }

    // Phase E: own chunk of key1 (j in [64,128)): exact u64 stable compare.
#pragma unroll 8
    for (int i = 32; i < 64; ++i) {
        const u64x2 kk = k2[i];
        asm("v_cmp_lt_u64 vcc, %[x], %[K]\n\t"
            "v_cmp_lt_u64 %[sc], %[y], %[K]\n\t"
            "v_addc_co_u32 %[r1], vcc, 0, %[r1], vcc\n\t"
            "v_addc_co_u32 %[r1], %[sc], 0, %[r1], %[sc]"
            : [r1]"+v"(r1), [sc]"=&s"(sc)
            : [x]"v"(kk.x), [y]"v"(kk.y), [K]"v"(K1)
            : "vcc");
    }

    // Ranks are distinct in [0,384). Output slot = #{selected ranks < r}.
    atomicOr(&bitmap[wave][r0 >> 5], 1u << (r0 & 31));
    atomicOr(&bitmap[wave][r1 >> 5], 1u << (r1 & 31));

    float* out_rays = out;
    float* out_mip  = out + (size_t)B * 768;

    {
        const int wi = (int)r0 >> 5;
        int s = __popc(bitmap[wave][wi] & ((1u << (r0 & 31)) - 1u));
        for (int w = 0; w < wi; ++w) s += __popc(bitmap[wave][w]);
        const size_t rb = (size_t)b * 768 + 384 + (size_t)s * 3;
        out_rays[rb + 0] = sdx[r0];
        out_rays[rb + 1] = sdy[r0];
        out_rays[rb + 2] = sdz[r0];
        out_mip[(size_t)b * 256 + 128 + s] = smip[r0];
    }
    {
        const int wi = (int)r1 >> 5;
        int s = __popc(bitmap[wave][wi] & ((1u << (r1 & 31)) - 1u));
        for (int w = 0; w < wi; ++w) s += __popc(bitmap[wave][w]);
        const size_t rb = (size_t)b * 768 + 384 + (size_t)s * 3;
        out_rays[rb + 0] = sdx[r1];
        out_rays[rb + 1] = sdy[r1];
        out_rays[rb + 2] = sdz[r1];
        out_mip[(size_t)b * 256 + 128 + s] = smip[r1];
    }

    // Pass-through copy stores (loads issued at kernel entry).
    float4* out4     = (float4*)out;
    float4* out_mip4 = (float4*)(out + (size_t)B * 768);
    if (off0 < 96) out4[(size_t)bb0 * 192 + off0] = c0;
    else           out_mip4[(size_t)bb0 * 64 + (off0 - 96)] = c0;
    if (off1 < 96) out4[(size_t)bb1 * 192 + off1] = c1;
    else           out_mip4[(size_t)bb1 * 64 + (off1 - 96)] = c1;
}

extern "C" void kernel_launch(void* const* d_in, const int* in_sizes, int n_in,
                              void* d_out, int out_size, void* d_ws, size_t ws_size,
                              hipStream_t stream) {
    const float* cache       = (const float*)d_in[0];
    const float* refdirs     = (const float*)d_in[1];
    const float* normal      = (const float*)d_in[2];
    const float* samp_rays   = (const float*)d_in[3];
    const float* samp_mipval = (const float*)d_in[4];
    float* out = (float*)d_out;

    const int B = in_sizes[1] / 3;  // 65536

    fused_kernel<<<B / 4, 256, 0, stream>>>(cache, refdirs, normal,
                                            (const float4*)samp_rays,
                                            (const float4*)samp_mipval,
                                            out, B);
}